// Round 1
// baseline (314.377 us; speedup 1.0000x reference)
//
#include <hip/hip_runtime.h>

#define IN_DIM 48
#define HID 32
#define ODIM 16

// ---------------------------------------------------------------------------
// Detect whether edge_index arrived as int64 (odd 32-bit words all zero) or
// int32. Writes stride (2 for int64, 1 for int32) into *flag. Single block,
// deterministic.
// ---------------------------------------------------------------------------
__global__ __launch_bounds__(256) void detect_kernel(const int* __restrict__ ei,
                                                     int n_edges, int* flag) {
    __shared__ int any;
    if (threadIdx.x == 0) any = 0;
    __syncthreads();
    int lim = n_edges < 4096 ? n_edges : 4096;
    int local = 0;
    for (int e = threadIdx.x; e < lim; e += 256) local |= ei[2 * e + 1];
    if (local) atomicOr(&any, 1);
    __syncthreads();
    if (threadIdx.x == 0) flag[0] = any ? 1 : 2;  // 1 = int32 layout, 2 = int64
}

// ---------------------------------------------------------------------------
// y = x @ w1.T  (w1 is [HID][IN_DIM] row-major);  also zero hpre.
// One thread per (node, j), j in [0,HID). W1^T staged in LDS (conflict-free:
// lane j hits bank j).
// ---------------------------------------------------------------------------
__global__ __launch_bounds__(256) void gemm1_kernel(const float* __restrict__ x,
        const float* __restrict__ w1, float* __restrict__ y,
        float* __restrict__ hpre, int n_nodes) {
    __shared__ float w1t[IN_DIM][HID];
    int tid = threadIdx.x;
    for (int i = tid; i < IN_DIM * HID; i += 256) {
        int j = i / IN_DIM, k = i % IN_DIM;
        w1t[k][j] = w1[i];
    }
    __syncthreads();
    int gid = blockIdx.x * 256 + tid;
    int n = gid >> 5;
    int j = gid & 31;
    if (n >= n_nodes) return;
    const float* xr = x + (size_t)n * IN_DIM;
    float acc = 0.f;
#pragma unroll
    for (int k = 0; k < IN_DIM; k += 4) {
        float4 xv = *reinterpret_cast<const float4*>(xr + k);
        acc += xv.x * w1t[k][j];
        acc += xv.y * w1t[k + 1][j];
        acc += xv.z * w1t[k + 2][j];
        acc += xv.w * w1t[k + 3][j];
    }
    y[(size_t)n * HID + j] = acc;
    hpre[(size_t)n * HID + j] = 0.f;
}

// ---------------------------------------------------------------------------
// scatter1: hpre[row] += y[col]  (32 floats per edge; lanes 0..31 = one edge)
// ---------------------------------------------------------------------------
__global__ __launch_bounds__(256) void scatter1_kernel(const int* __restrict__ ei,
        const float* __restrict__ y, float* __restrict__ hpre,
        const int* __restrict__ flag, int n_edges, int n_nodes) {
    int gid = blockIdx.x * 256 + threadIdx.x;
    int e = gid >> 5;
    int d = gid & 31;
    if (e >= n_edges) return;
    int s = flag[0];
    int row = ei[(size_t)s * e];
    int col = ei[(size_t)s * (n_edges + e)];
    if ((unsigned)row >= (unsigned)n_nodes || (unsigned)col >= (unsigned)n_nodes) return;
    float v = y[(size_t)col * HID + d];
    unsafeAtomicAdd(&hpre[(size_t)row * HID + d], v);
}

// ---------------------------------------------------------------------------
// z = relu(hpre + b1) @ w2.T  (w2 is [ODIM][HID]); also out = b2 (init).
// One thread per (node, j), j in [0,ODIM).
// ---------------------------------------------------------------------------
__global__ __launch_bounds__(256) void gemm2_kernel(const float* __restrict__ hpre,
        const float* __restrict__ b1, const float* __restrict__ w2,
        const float* __restrict__ b2, float* __restrict__ z,
        float* __restrict__ out, int n_nodes) {
    __shared__ float w2t[HID][ODIM];
    __shared__ float b1s[HID];
    int tid = threadIdx.x;
    for (int i = tid; i < HID * ODIM; i += 256) {
        int j = i / HID, k = i % HID;
        w2t[k][j] = w2[i];
    }
    if (tid < HID) b1s[tid] = b1[tid];
    __syncthreads();
    int gid = blockIdx.x * 256 + tid;
    int n = gid >> 4;
    int j = gid & 15;
    if (n >= n_nodes) return;
    const float* hr = hpre + (size_t)n * HID;
    float acc = 0.f;
#pragma unroll
    for (int k = 0; k < HID; k += 4) {
        float4 hv = *reinterpret_cast<const float4*>(hr + k);
        float h0 = fmaxf(hv.x + b1s[k], 0.f);
        float h1 = fmaxf(hv.y + b1s[k + 1], 0.f);
        float h2 = fmaxf(hv.z + b1s[k + 2], 0.f);
        float h3 = fmaxf(hv.w + b1s[k + 3], 0.f);
        acc += h0 * w2t[k][j];
        acc += h1 * w2t[k + 1][j];
        acc += h2 * w2t[k + 2][j];
        acc += h3 * w2t[k + 3][j];
    }
    z[(size_t)n * ODIM + j] = acc;
    out[(size_t)n * ODIM + j] = b2[j];
}

// ---------------------------------------------------------------------------
// scatter2: out[row] += z[col]  (16 floats per edge)
// ---------------------------------------------------------------------------
__global__ __launch_bounds__(256) void scatter2_kernel(const int* __restrict__ ei,
        const float* __restrict__ z, float* __restrict__ out,
        const int* __restrict__ flag, int n_edges, int n_nodes) {
    int gid = blockIdx.x * 256 + threadIdx.x;
    int e = gid >> 4;
    int d = gid & 15;
    if (e >= n_edges) return;
    int s = flag[0];
    int row = ei[(size_t)s * e];
    int col = ei[(size_t)s * (n_edges + e)];
    if ((unsigned)row >= (unsigned)n_nodes || (unsigned)col >= (unsigned)n_nodes) return;
    float v = z[(size_t)col * ODIM + d];
    unsafeAtomicAdd(&out[(size_t)row * ODIM + d], v);
}

extern "C" void kernel_launch(void* const* d_in, const int* in_sizes, int n_in,
                              void* d_out, int out_size, void* d_ws, size_t ws_size,
                              hipStream_t stream) {
    const float* x  = (const float*)d_in[0];
    const int*   ei = (const int*)d_in[1];
    const float* w1 = (const float*)d_in[2];
    const float* b1 = (const float*)d_in[3];
    const float* w2 = (const float*)d_in[4];
    const float* b2 = (const float*)d_in[5];
    float* out = (float*)d_out;

    int n_nodes = in_sizes[0] / IN_DIM;
    int n_edges = in_sizes[1] / 2;

    float* y    = (float*)d_ws;                       // [N, 32]
    float* hpre = y + (size_t)n_nodes * HID;          // [N, 32]
    float* z    = y;                                  // alias y (dead after scatter1)
    int*   flag = (int*)(hpre + (size_t)n_nodes * HID);

    detect_kernel<<<1, 256, 0, stream>>>(ei, n_edges, flag);

    {
        int total = n_nodes * HID;
        int blocks = (total + 255) / 256;
        gemm1_kernel<<<blocks, 256, 0, stream>>>(x, w1, y, hpre, n_nodes);
    }
    {
        long long total = (long long)n_edges * HID;
        int blocks = (int)((total + 255) / 256);
        scatter1_kernel<<<blocks, 256, 0, stream>>>(ei, y, hpre, flag, n_edges, n_nodes);
    }
    {
        int total = n_nodes * ODIM;
        int blocks = (total + 255) / 256;
        gemm2_kernel<<<blocks, 256, 0, stream>>>(hpre, b1, w2, b2, z, out, n_nodes);
    }
    {
        long long total = (long long)n_edges * ODIM;
        int blocks = (int)((total + 255) / 256);
        scatter2_kernel<<<blocks, 256, 0, stream>>>(ei, z, out, flag, n_edges, n_nodes);
    }
}